// Round 2
// baseline (1820.135 us; speedup 1.0000x reference)
//
#include <hip/hip_runtime.h>

#define B_ 2
#define H_ 16
#define S_ 2048
#define D_ 128

typedef __attribute__((ext_vector_type(8))) short short8;
typedef __attribute__((ext_vector_type(4))) float floatx4;

__device__ __forceinline__ unsigned short f2bf(float f) {
    union { float f; unsigned int u; } c; c.f = f;
    unsigned int u = c.u;
    u += 0x7fff + ((u >> 16) & 1);   // round-to-nearest-even
    return (unsigned short)(u >> 16);
}

// ---------------------------------------------------------------------------
// Prep 0: K fp32 [bh][s][d] -> bf16 same layout (workspace).
// ---------------------------------------------------------------------------
__global__ __launch_bounds__(256) void kbf_kernel(const float* __restrict__ k,
                                                  unsigned short* __restrict__ kw) {
    int base = blockIdx.x * 1024 + threadIdx.x;
    #pragma unroll
    for (int i = 0; i < 4; ++i) {
        int idx = base + i * 256;
        const float4* s = (const float4*)k + (size_t)idx * 2;
        float4 a = s[0], c = s[1];
        short8 y;
        y[0] = f2bf(a.x); y[1] = f2bf(a.y); y[2] = f2bf(a.z); y[3] = f2bf(a.w);
        y[4] = f2bf(c.x); y[5] = f2bf(c.y); y[6] = f2bf(c.z); y[7] = f2bf(c.w);
        ((short8*)kw)[idx] = y;
    }
}

// ---------------------------------------------------------------------------
// Prep 1: V fp32 [bh][s][d] -> V^T bf16 [bh][d][s] (workspace).
// ---------------------------------------------------------------------------
__global__ __launch_bounds__(256) void vt_kernel(const float* __restrict__ v,
                                                 unsigned short* __restrict__ vt) {
    __shared__ unsigned short tl[128][66];
    int bid = blockIdx.x;
    int bh = bid >> 5;
    int s0 = (bid & 31) << 6;
    int t = threadIdx.x;
    const float4* vp = (const float4*)(v + ((size_t)bh * S_ + s0) * D_);
    #pragma unroll
    for (int i = 0; i < 8; ++i) {
        int idx = t + i * 256;
        int r = idx >> 5;
        int d = (idx & 31) << 2;
        float4 x = vp[idx];
        tl[d + 0][r] = f2bf(x.x);
        tl[d + 1][r] = f2bf(x.y);
        tl[d + 2][r] = f2bf(x.z);
        tl[d + 3][r] = f2bf(x.w);
    }
    __syncthreads();
    unsigned short* op = vt + (size_t)bh * D_ * S_ + s0;
    #pragma unroll
    for (int i = 0; i < 16; ++i) {
        int idx = t + i * 256;
        int d = idx >> 5;
        int s2 = (idx & 31) << 1;
        unsigned int val = (unsigned int)tl[d][s2] | ((unsigned int)tl[d][s2 + 1] << 16);
        *(unsigned int*)(op + (size_t)d * S_ + s2) = val;
    }
}

// ---------------------------------------------------------------------------
// Fused attention, BARRIER-FREE main loop.
// Waves are fully independent (each owns 16 q-rows).  K and V MFMA
// B-fragments are loaded per-lane directly from the L2-resident bf16
// workspaces (no LDS staging, no __syncthreads -> no vmcnt(0) drains; the
// compiler is free to keep many loads in flight across k-tiles).  The only
// LDS is a 2 KB wave-private buffer for the P acc-layout -> A-frag-layout
// transpose (same-wave lgkmcnt ordering only).
// Mask is folded into the bias register at load: bb = m ? bias : -1e30
// (exp underflows to exact 0), saving 16 VGPRs and hot-path cndmasks.
// Phase 1 accumulates per-row sum(exp) in registers; phase 2 recomputes QK,
// writes normalized attn once, and accumulates out = P@V.
// ---------------------------------------------------------------------------

#define LOAD_BM(BB, K0) do {                                                  \
    _Pragma("unroll") for (int rr = 0; rr < 4; ++rr) {                        \
        _Pragma("unroll") for (int nt = 0; nt < 4; ++nt) {                    \
            int m_ = mask_r[rr][(K0) + nt * 16];                              \
            float bv_ = bias_r[rr][(K0) + nt * 16];                           \
            BB[rr * 4 + nt] = m_ ? bv_ : -1e30f; } } } while (0)

#define QK_MFMA(K0, ACC) do {                                                 \
    _Pragma("unroll") for (int nt = 0; nt < 4; ++nt)                          \
        ACC[nt] = (floatx4){0.f, 0.f, 0.f, 0.f};                              \
    _Pragma("unroll") for (int kk = 0; kk < 4; ++kk) {                        \
        _Pragma("unroll") for (int nt = 0; nt < 4; ++nt) {                    \
            short8 bfr_ = *(const short8*)(kfrag + (K0) * 256 +               \
                                           nt * 4096 + kk * 64);              \
            ACC[nt] = __builtin_amdgcn_mfma_f32_16x16x32_bf16(                \
                          afr[kk], bfr_, ACC[nt], 0, 0, 0); } } } while (0)

#define ERS(BB) do {                                                          \
    _Pragma("unroll") for (int rr = 0; rr < 4; ++rr) {                        \
        _Pragma("unroll") for (int nt = 0; nt < 4; ++nt) {                    \
            rs[rr] += __expf(fmaf(acc[nt][rr], scale, BB[rr * 4 + nt]));      \
        } } } while (0)

// QK -> normalized p -> attn store + pbuf stash -> PV accumulate.
// pbuf WAR/RAW hazards are same-wave program-order (compiler lgkmcnt).
#define STEP(K0, BB) do {                                                     \
    floatx4 acc[4];                                                           \
    QK_MFMA(K0, acc);                                                         \
    _Pragma("unroll") for (int rr = 0; rr < 4; ++rr) {                        \
        _Pragma("unroll") for (int nt = 0; nt < 4; ++nt) {                    \
            float pv_ = __expf(fmaf(acc[nt][rr], scale, BB[rr * 4 + nt]))     \
                        * rinv[rr];                                           \
            attn_r[rr * S_ + (K0) + nt * 16] = pv_;                           \
            int prow_ = g * 4 + rr;                                           \
            *(unsigned short*)(pbase + prow_ * 128 +                          \
                ((nt * 32 + (l16 << 1)) ^ ((prow_ & 7) << 4))) = f2bf(pv_);   \
        } }                                                                   \
    _Pragma("unroll") for (int kk = 0; kk < 2; ++kk) {                        \
        short8 pa_ = *(const short8*)(pbase + l16 * 128 +                     \
                        ((kk * 64 + g * 16) ^ ((l16 & 7) << 4)));             \
        _Pragma("unroll") for (int nt = 0; nt < 8; ++nt) {                    \
            short8 vf_ = *(const short8*)(vfrag + nt * 65536 +                \
                                          (K0) * 2 + kk * 64);                \
            oacc[nt] = __builtin_amdgcn_mfma_f32_16x16x32_bf16(               \
                           pa_, vf_, oacc[nt], 0, 0, 0); } } } while (0)

__global__ __launch_bounds__(256, 3) void attn_kernel(
    const float* __restrict__ q,
    const int* __restrict__ mask,
    const float* __restrict__ bias,
    const unsigned short* __restrict__ ktw,
    const unsigned short* __restrict__ vtw,
    float* __restrict__ attn,
    float* __restrict__ out)
{
    __shared__ __align__(16) char smem[8192];   // 2 KB per wave, wave-private

    int bid = blockIdx.x;
    int qt = bid >> 5;
    int hb = bid & 31;          // bid%8 == hb&7 -> all 32 q-tiles of an (h,b)
    int h = hb >> 1;            // land on one XCD: bias/K/V L2 locality free.
    int b = hb & 1;
    int bh = b * H_ + h;
    int q0 = qt << 6;
    int t = threadIdx.x;
    int w = t >> 6;
    int lane = t & 63;
    int g = lane >> 4;
    int l16 = lane & 15;

    // per-lane fragment base pointers into the bf16 workspaces
    const char* kfrag = (const char*)(ktw + (size_t)bh * S_ * D_)
                        + l16 * 256 + g * 16;
    const char* vfrag = (const char*)(vtw + (size_t)bh * D_ * S_)
                        + l16 * 4096 + g * 16;
    char* pbase = smem + (w << 11);

    // Q A-fragments (loop-invariant): lane(g,l16) holds Q[q0+w*16+l16][kk*32+g*8+j]
    short8 afr[4];
    {
        const float* qrow = q + ((size_t)bh * S_ + q0 + w * 16 + l16) * D_;
        #pragma unroll
        for (int kk = 0; kk < 4; ++kk) {
            float4 a = *(const float4*)&qrow[kk * 32 + g * 8];
            float4 c = *(const float4*)&qrow[kk * 32 + g * 8 + 4];
            short8 f;
            f[0] = f2bf(a.x); f[1] = f2bf(a.y); f[2] = f2bf(a.z); f[3] = f2bf(a.w);
            f[4] = f2bf(c.x); f[5] = f2bf(c.y); f[6] = f2bf(c.z); f[7] = f2bf(c.w);
            afr[kk] = f;
        }
    }

    // bias/mask per-lane row pointers in accumulator layout:
    // rows q0+w*16+g*4+rr, col = l16 (+ k0 + nt*16 at load time)
    const float* bias_r[4];
    const int*   mask_r[4];
    {
        const float* bh_bias = bias + (size_t)h * S_ * S_;
        const int*   b_mask  = mask + (size_t)b * S_ * S_;
        #pragma unroll
        for (int rr = 0; rr < 4; ++rr) {
            int row = q0 + w * 16 + g * 4 + rr;
            bias_r[rr] = bh_bias + (size_t)row * S_ + l16;
            mask_r[rr] = b_mask  + (size_t)row * S_ + l16;
        }
    }

    const float scale = 0.08838834764831845f;  // 1/sqrt(128)
    float rs[4] = {0.f, 0.f, 0.f, 0.f};
    float bbA[16], bbB[16];

    // ---------------- phase 1: row sums only (no barriers) ----------------
    LOAD_BM(bbA, 0);
    #pragma unroll 1
    for (int ktp = 0; ktp < 16; ++ktp) {
        int k0 = ktp << 7;
        LOAD_BM(bbB, k0 + 64);
        {
            floatx4 acc[4];
            QK_MFMA(k0, acc);
            ERS(bbA);
        }
        if (ktp < 15) LOAD_BM(bbA, k0 + 128);
        {
            floatx4 acc[4];
            QK_MFMA(k0 + 64, acc);
            ERS(bbB);
        }
    }

    // reduce row sums across the 16 lanes sharing each row; rinv in registers
    float rinv[4];
    #pragma unroll
    for (int rr = 0; rr < 4; ++rr) {
        float s = rs[rr];
        s += __shfl_xor(s, 1, 16);
        s += __shfl_xor(s, 2, 16);
        s += __shfl_xor(s, 4, 16);
        s += __shfl_xor(s, 8, 16);
        rinv[rr] = s > 0.f ? 1.0f / s : 0.f;
    }

    // ---------------- phase 2: normalized attn + PV (no barriers) ----------
    floatx4 oacc[8];
    #pragma unroll
    for (int nt = 0; nt < 8; ++nt) oacc[nt] = (floatx4){0.f, 0.f, 0.f, 0.f};

    float* attn_r = attn + (size_t)bh * S_ * S_
                  + (size_t)(q0 + w * 16 + g * 4) * S_ + l16;

    LOAD_BM(bbA, 0);
    #pragma unroll 1
    for (int ktp = 0; ktp < 16; ++ktp) {
        int k0 = ktp << 7;
        LOAD_BM(bbB, k0 + 64);
        STEP(k0, bbA);
        if (ktp < 15) LOAD_BM(bbA, k0 + 128);
        STEP(k0 + 64, bbB);
    }

    float* op = out + ((size_t)bh * S_ + q0 + w * 16 + g * 4) * D_ + l16;
    #pragma unroll
    for (int nt = 0; nt < 8; ++nt)
        #pragma unroll
        for (int rr = 0; rr < 4; ++rr)
            op[(size_t)rr * D_ + nt * 16] = oacc[nt][rr];
}

extern "C" void kernel_launch(void* const* d_in, const int* in_sizes, int n_in,
                              void* d_out, int out_size, void* d_ws, size_t ws_size,
                              hipStream_t stream) {
    (void)in_sizes; (void)n_in; (void)out_size; (void)ws_size;
    const float* q    = (const float*)d_in[0];
    const float* k    = (const float*)d_in[1];
    const float* v    = (const float*)d_in[2];
    const int*   mask = (const int*)d_in[3];
    const float* bias = (const float*)d_in[4];

    float* out  = (float*)d_out;
    float* attn = out + (size_t)B_ * H_ * S_ * D_;

    // workspace: K-bf16 (16 MiB) + V^T-bf16 (16 MiB) = 32 MiB
    unsigned short* ktw = (unsigned short*)d_ws;
    unsigned short* vtw = ktw + (size_t)B_ * H_ * S_ * D_;

    kbf_kernel<<<1024, 256, 0, stream>>>(k, ktw);
    vt_kernel<<<1024, 256, 0, stream>>>(v, vtw);
    attn_kernel<<<1024, 256, 0, stream>>>(q, mask, bias, ktw, vtw, attn, out);
}

// Round 4
// 1214.629 us; speedup vs baseline: 1.4985x; 1.4985x over previous
//
#include <hip/hip_runtime.h>

#define B_ 2
#define H_ 16
#define S_ 2048
#define D_ 128

typedef __attribute__((ext_vector_type(8))) short short8;
typedef __attribute__((ext_vector_type(4))) float floatx4;

#define FENCE() asm volatile("" ::: "memory")

__device__ __forceinline__ unsigned short f2bf(float f) {
    union { float f; unsigned int u; } c; c.f = f;
    unsigned int u = c.u;
    u += 0x7fff + ((u >> 16) & 1);   // round-to-nearest-even
    return (unsigned short)(u >> 16);
}

// async global->LDS, 16 B/lane. LDS dest = wave-uniform base + lane*16 (m104).
__device__ __forceinline__ void gld16(const void* g, void* l) {
    __builtin_amdgcn_global_load_lds(
        (const __attribute__((address_space(1))) unsigned int*)(unsigned long long)g,
        (__attribute__((address_space(3))) unsigned int*)(unsigned int)(unsigned long long)l,
        16, 0, 0);
}

// ---------------------------------------------------------------------------
// Prep 0: K fp32 [bh][s][d] -> bf16 same layout (workspace).
// ---------------------------------------------------------------------------
__global__ __launch_bounds__(256) void kbf_kernel(const float* __restrict__ k,
                                                  unsigned short* __restrict__ kw) {
    int base = blockIdx.x * 1024 + threadIdx.x;
    #pragma unroll
    for (int i = 0; i < 4; ++i) {
        int idx = base + i * 256;
        const float4* s = (const float4*)k + (size_t)idx * 2;
        float4 a = s[0], c = s[1];
        short8 y;
        y[0] = f2bf(a.x); y[1] = f2bf(a.y); y[2] = f2bf(a.z); y[3] = f2bf(a.w);
        y[4] = f2bf(c.x); y[5] = f2bf(c.y); y[6] = f2bf(c.z); y[7] = f2bf(c.w);
        ((short8*)kw)[idx] = y;
    }
}

// ---------------------------------------------------------------------------
// Prep 1: V fp32 [bh][s][d] -> V^T bf16 [bh][d][s] (workspace).
// ---------------------------------------------------------------------------
__global__ __launch_bounds__(256) void vt_kernel(const float* __restrict__ v,
                                                 unsigned short* __restrict__ vt) {
    __shared__ unsigned short tl[128][66];
    int bid = blockIdx.x;
    int bh = bid >> 5;
    int s0 = (bid & 31) << 6;
    int t = threadIdx.x;
    const float4* vp = (const float4*)(v + ((size_t)bh * S_ + s0) * D_);
    #pragma unroll
    for (int i = 0; i < 8; ++i) {
        int idx = t + i * 256;
        int r = idx >> 5;
        int d = (idx & 31) << 2;
        float4 x = vp[idx];
        tl[d + 0][r] = f2bf(x.x);
        tl[d + 1][r] = f2bf(x.y);
        tl[d + 2][r] = f2bf(x.z);
        tl[d + 3][r] = f2bf(x.w);
    }
    __syncthreads();
    unsigned short* op = vt + (size_t)bh * D_ * S_ + s0;
    #pragma unroll
    for (int i = 0; i < 16; ++i) {
        int idx = t + i * 256;
        int d = idx >> 5;
        int s2 = (idx & 31) << 1;
        unsigned int val = (unsigned int)tl[d][s2] | ((unsigned int)tl[d][s2 + 1] << 16);
        *(unsigned int*)(op + (size_t)d * S_ + s2) = val;
    }
}

// ---------------------------------------------------------------------------
// Fused attention with T3/T4 pipelined schedule (counted vmcnt, never 0 in
// the main loop).  Round-1 structure (coalesced global_load_lds staging of
// K/V, LDS-swizzled, reg bias/mask, pbuf P-transpose) but:
//  * stage for tile t+1 is issued at the TOP of iter t -> HBM/L2 latency
//    hides under QK MFMA + exp + PV MFMA;
//  * __syncthreads() replaced by asm s_waitcnt vmcnt(N) + raw s_barrier.
//    N counts the memory ops issued after the 8 staging ops (32 bias/mask
//    loads + 16 attn stores = 48 in phase 2; 32 in phase 1) minus a safety
//    margin of 4 (tolerates the compiler emitting slightly fewer counted
//    ops; in-order completion makes over-waiting ~free).  Only the staging
//    is forced complete - bias/mask prefetch and the store stream stay in
//    flight across barriers;
//  * K AND V double-buffered (LDS 72 KB -> 2 blocks/CU, per-wave ILP
//    replaces TLP);
//  * s_setprio(1) around MFMA clusters (T5; phase-split now exists);
//  * nontemporal attn stores + bias loads (streams; keep K/V/mask
//    L2-resident).
// Issue order inside an iter is pinned by memory-clobber asm fences; no
// counted load/store is merge-able (all 64 B-strided) and no spills are
// possible (<=2 waves/SIMD -> 256 VGPR budget), so counts are stable.
// ---------------------------------------------------------------------------

#define LOAD_BM(BB, K0) do {                                                  \
    _Pragma("unroll") for (int rr = 0; rr < 4; ++rr) {                        \
        _Pragma("unroll") for (int nt = 0; nt < 4; ++nt) {                    \
            int m_ = mask_r[rr][(K0) + nt * 16];                              \
            float bv_ = __builtin_nontemporal_load(                           \
                            &bias_r[rr][(K0) + nt * 16]);                     \
            BB[rr * 4 + nt] = m_ ? bv_ : -1e30f; } } } while (0)

#define QK_MFMA(KB, ACC) do {                                                 \
    _Pragma("unroll") for (int nt = 0; nt < 4; ++nt)                          \
        ACC[nt] = (floatx4){0.f, 0.f, 0.f, 0.f};                              \
    _Pragma("unroll") for (int kk = 0; kk < 4; ++kk) {                        \
        _Pragma("unroll") for (int nt = 0; nt < 4; ++nt) {                    \
            int r_ = nt * 16 + l16;                                           \
            short8 bfr_ = *(const short8*)((const char*)(KB) + r_ * 256 +     \
                           ((kk * 64 + g * 16) ^ ((r_ & 7) << 4)));           \
            ACC[nt] = __builtin_amdgcn_mfma_f32_16x16x32_bf16(                \
                          afr[kk], bfr_, ACC[nt], 0, 0, 0); } } } while (0)

#define ERS(BB) do {                                                          \
    _Pragma("unroll") for (int rr = 0; rr < 4; ++rr) {                        \
        _Pragma("unroll") for (int nt = 0; nt < 4; ++nt) {                    \
            rs[rr] += __expf(fmaf(acc[nt][rr], scale, BB[rr * 4 + nt]));      \
        } } } while (0)

// QK -> normalized p -> attn store + pbuf stash -> PV accumulate.
#define STEP(K0, BB, KB, VB) do {                                             \
    floatx4 acc[4];                                                           \
    __builtin_amdgcn_s_setprio(1);                                            \
    QK_MFMA(KB, acc);                                                         \
    __builtin_amdgcn_s_setprio(0);                                            \
    _Pragma("unroll") for (int rr = 0; rr < 4; ++rr) {                        \
        _Pragma("unroll") for (int nt = 0; nt < 4; ++nt) {                    \
            float pv_ = __expf(fmaf(acc[nt][rr], scale, BB[rr * 4 + nt]))     \
                        * rinv[rr];                                           \
            __builtin_nontemporal_store(pv_,                                  \
                &attn_r[rr * S_ + (K0) + nt * 16]);                           \
            int prow_ = g * 4 + rr;                                           \
            *(unsigned short*)(pbase + prow_ * 128 +                          \
                ((nt * 32 + (l16 << 1)) ^ ((prow_ & 7) << 4))) = f2bf(pv_);   \
        } }                                                                   \
    __builtin_amdgcn_s_setprio(1);                                            \
    _Pragma("unroll") for (int kk = 0; kk < 2; ++kk) {                        \
        short8 pa_ = *(const short8*)(pbase + l16 * 128 +                     \
                        ((kk * 64 + g * 16) ^ ((l16 & 7) << 4)));             \
        _Pragma("unroll") for (int nt = 0; nt < 8; ++nt) {                    \
            int d_ = nt * 16 + l16;                                           \
            short8 vf_ = *(const short8*)((const char*)(VB) + d_ * 128 +      \
                          ((kk * 64 + g * 16) ^ ((d_ & 7) << 4)));            \
            oacc[nt] = __builtin_amdgcn_mfma_f32_16x16x32_bf16(               \
                           pa_, vf_, oacc[nt], 0, 0, 0); } }                  \
    __builtin_amdgcn_s_setprio(0);                                            \
} while (0)

#define WAITBAR(N) do {                                                       \
    asm volatile("s_waitcnt vmcnt(" #N ")" ::: "memory");                     \
    __builtin_amdgcn_s_barrier();                                             \
    FENCE();                                                                  \
} while (0)

__global__ __launch_bounds__(256, 2) void attn_kernel(
    const float* __restrict__ q,
    const int* __restrict__ mask,
    const float* __restrict__ bias,
    const unsigned short* __restrict__ ktw,
    const unsigned short* __restrict__ vtw,
    float* __restrict__ attn,
    float* __restrict__ out)
{
    __shared__ __align__(16) char smem[73728];
    char* kb0 = smem;                    // K tile 64x128 bf16, swizzled
    char* kb1 = smem + 16384;
    char* vb0 = smem + 32768;            // V^T tile 128x64 bf16, swizzled
    char* vb1 = smem + 49152;
    char* pall = smem + 65536;           // 4 x 2 KB wave-private P buffers

    int bid = blockIdx.x;
    int qt = bid >> 5;
    int hb = bid & 31;          // bid%8 == hb&7 -> all 32 q-tiles of an (h,b)
    int h = hb >> 1;            // land on one XCD: bias/K/V L2 locality free.
    int b = hb & 1;
    int bh = b * H_ + h;
    int q0 = qt << 6;
    int t = threadIdx.x;
    int w = t >> 6;
    int lane = t & 63;
    int g = lane >> 4;
    int l16 = lane & 15;

    const char* ktw_bh = (const char*)(ktw + (size_t)bh * S_ * D_);
    const char* vtw_bh = (const char*)(vtw + (size_t)bh * D_ * S_);
    char* pbase = pall + (w << 11);

    // Q A-fragments (loop-invariant): lane(g,l16) holds Q[q0+w*16+l16][kk*32+g*8+j]
    short8 afr[4];
    {
        const float* qrow = q + ((size_t)bh * S_ + q0 + w * 16 + l16) * D_;
        #pragma unroll
        for (int kk = 0; kk < 4; ++kk) {
            float4 a = *(const float4*)&qrow[kk * 32 + g * 8];
            float4 c = *(const float4*)&qrow[kk * 32 + g * 8 + 4];
            short8 f;
            f[0] = f2bf(a.x); f[1] = f2bf(a.y); f[2] = f2bf(a.z); f[3] = f2bf(a.w);
            f[4] = f2bf(c.x); f[5] = f2bf(c.y); f[6] = f2bf(c.z); f[7] = f2bf(c.w);
            afr[kk] = f;
        }
    }

    // bias/mask per-lane row pointers in accumulator layout:
    // rows q0+w*16+g*4+rr, col = l16 (+ k0 + nt*16 at load time)
    const float* bias_r[4];
    const int*   mask_r[4];
    {
        const float* bh_bias = bias + (size_t)h * S_ * S_;
        const int*   b_mask  = mask + (size_t)b * S_ * S_;
        #pragma unroll
        for (int rr = 0; rr < 4; ++rr) {
            int row = q0 + w * 16 + g * 4 + rr;
            bias_r[rr] = bh_bias + (size_t)row * S_ + l16;
            mask_r[rr] = b_mask  + (size_t)row * S_ + l16;
        }
    }

    // staging: wave w covers its quarter; source address carries the inverse
    // swizzle so linear LDS writes land swizzled (m173).
    auto stage_k = [&](int k0, char* kb) {
        int rsub = lane >> 4;
        int cb = (lane & 15) << 4;
        #pragma unroll
        for (int c = 0; c < 4; ++c) {
            int r = w * 16 + c * 4 + rsub;
            const char* src = ktw_bh + (((size_t)(k0 + r)) << 8)
                              + (cb ^ ((r & 7) << 4));
            gld16(src, kb + w * 4096 + c * 1024);
        }
    };
    auto stage_v = [&](int k0, char* vb) {
        int dsub = lane >> 3;
        int cb = (lane & 7) << 4;
        #pragma unroll
        for (int c = 0; c < 4; ++c) {
            int d = w * 32 + c * 8 + dsub;
            const char* src = vtw_bh + ((size_t)d << 12)
                              + (size_t)(k0 * 2) + (cb ^ ((d & 7) << 4));
            gld16(src, vb + w * 4096 + c * 1024);
        }
    };

    const float scale = 0.08838834764831845f;  // 1/sqrt(128)
    float rs[4] = {0.f, 0.f, 0.f, 0.f};
    float bbA[16], bbB[16];

    // ---------------- phase 1: row sums only ----------------
    stage_k(0, kb0);
    FENCE();
    LOAD_BM(bbA, 0);
    asm volatile("s_waitcnt vmcnt(0)" ::: "memory");
    __builtin_amdgcn_s_barrier();
    FENCE();

    #pragma unroll 1
    for (int ktp = 0; ktp < 16; ++ktp) {
        int k0 = ktp << 7;
        // even: compute tile k0 from kb0; stage k0+64 -> kb1
        stage_k(k0 + 64, kb1);
        FENCE();
        LOAD_BM(bbB, k0 + 64);
        {
            floatx4 acc[4];
            __builtin_amdgcn_s_setprio(1);
            QK_MFMA(kb0, acc);
            __builtin_amdgcn_s_setprio(0);
            ERS(bbA);
        }
        WAITBAR(28);   // 32 b/m loads after the 4 stage ops; margin 4
        // odd: compute tile k0+64 from kb1; stage k0+128 -> kb0
        if (ktp < 15) {
            stage_k(k0 + 128, kb0);
            FENCE();
            LOAD_BM(bbA, k0 + 128);
        }
        {
            floatx4 acc[4];
            __builtin_amdgcn_s_setprio(1);
            QK_MFMA(kb1, acc);
            __builtin_amdgcn_s_setprio(0);
            ERS(bbB);
        }
        WAITBAR(28);
    }

    // reduce row sums across the 16 lanes sharing each row; rinv in registers
    float rinv[4];
    #pragma unroll
    for (int rr = 0; rr < 4; ++rr) {
        float s = rs[rr];
        s += __shfl_xor(s, 1, 16);
        s += __shfl_xor(s, 2, 16);
        s += __shfl_xor(s, 4, 16);
        s += __shfl_xor(s, 8, 16);
        rinv[rr] = s > 0.f ? 1.0f / s : 0.f;
    }

    // ---------------- phase 2: normalized attn + PV ----------------
    floatx4 oacc[8];
    #pragma unroll
    for (int nt = 0; nt < 8; ++nt) oacc[nt] = (floatx4){0.f, 0.f, 0.f, 0.f};

    float* attn_r = attn + (size_t)bh * S_ * S_
                  + (size_t)(q0 + w * 16 + g * 4) * S_ + l16;

    stage_k(0, kb0);
    stage_v(0, vb0);
    FENCE();
    LOAD_BM(bbA, 0);
    asm volatile("s_waitcnt vmcnt(0)" ::: "memory");
    __builtin_amdgcn_s_barrier();
    FENCE();

    #pragma unroll 1
    for (int ktp = 0; ktp < 16; ++ktp) {
        int k0 = ktp << 7;
        // even: compute tile k0 from kb0/vb0; stage k0+64 -> kb1/vb1
        stage_k(k0 + 64, kb1);
        stage_v(k0 + 64, vb1);
        FENCE();
        LOAD_BM(bbB, k0 + 64);
        STEP(k0, bbA, kb0, vb0);
        WAITBAR(44);   // 32 b/m loads + 16 attn stores after 8 stage ops; margin 4
        // odd: compute tile k0+64 from kb1/vb1; stage k0+128 -> kb0/vb0
        if (ktp < 15) {
            stage_k(k0 + 128, kb0);
            stage_v(k0 + 128, vb0);
            FENCE();
            LOAD_BM(bbA, k0 + 128);
        }
        STEP(k0 + 64, bbB, kb1, vb1);
        WAITBAR(44);
    }

    float* op = out + ((size_t)bh * S_ + q0 + w * 16 + g * 4) * D_ + l16;
    #pragma unroll
    for (int nt = 0; nt < 8; ++nt)
        #pragma unroll
        for (int rr = 0; rr < 4; ++rr)
            op[(size_t)rr * D_ + nt * 16] = oacc[nt][rr];
}

extern "C" void kernel_launch(void* const* d_in, const int* in_sizes, int n_in,
                              void* d_out, int out_size, void* d_ws, size_t ws_size,
                              hipStream_t stream) {
    (void)in_sizes; (void)n_in; (void)out_size; (void)ws_size;
    const float* q    = (const float*)d_in[0];
    const float* k    = (const float*)d_in[1];
    const float* v    = (const float*)d_in[2];
    const int*   mask = (const int*)d_in[3];
    const float* bias = (const float*)d_in[4];

    float* out  = (float*)d_out;
    float* attn = out + (size_t)B_ * H_ * S_ * D_;

    // workspace: K-bf16 (16 MiB) + V^T-bf16 (16 MiB) = 32 MiB
    unsigned short* ktw = (unsigned short*)d_ws;
    unsigned short* vtw = ktw + (size_t)B_ * H_ * S_ * D_;

    kbf_kernel<<<1024, 256, 0, stream>>>(k, ktw);
    vt_kernel<<<1024, 256, 0, stream>>>(v, vtw);
    attn_kernel<<<1024, 256, 0, stream>>>(q, mask, bias, ktw, vtw, attn, out);
}